// Round 3
// baseline (112.287 us; speedup 1.0000x reference)
//
#include <hip/hip_runtime.h>
#include <hip/hip_bf16.h>
#include <stdint.h>

#define FEAT 1024
#define NALL 1000
#define NPAD 1120
#define NCLS 100
#define LDSBUF 28672   // A 256x32 bf16 (16384 B) + B 192x32 bf16 (12288 B)

typedef __attribute__((ext_vector_type(8))) short short8;
typedef __attribute__((ext_vector_type(4))) float f32x4;
typedef __attribute__((ext_vector_type(4))) unsigned short us4;

__device__ __forceinline__ unsigned short f2bf(float f) {
    union { float f; uint32_t u; } v; v.f = f;
    uint32_t u = v.u;
    return (unsigned short)((u + 0x7FFFu + ((u >> 16) & 1u)) >> 16);
}

__device__ __forceinline__ void gload16(const void* g, void* l) {
    __builtin_amdgcn_global_load_lds((__attribute__((address_space(1))) void*)g,
                                     (__attribute__((address_space(3))) void*)l,
                                     16, 0, 0);
}

// K1: x (16384x1024 f32) -> bf16, plus row sum-of-squares
__global__ __launch_bounds__(256) void k_prep_x(const float* __restrict__ x,
                                                unsigned short* __restrict__ xb,
                                                float* __restrict__ xsq) {
    int row = blockIdx.x * 4 + (threadIdx.x >> 6);
    int lane = threadIdx.x & 63;
    const float4* xr = (const float4*)(x + (size_t)row * FEAT);
    float s = 0.f;
#pragma unroll
    for (int i = 0; i < 4; ++i) {
        float4 v = xr[lane + i * 64];
        s += v.x * v.x + v.y * v.y + v.z * v.z + v.w * v.w;
        us4 o;
        o[0] = f2bf(v.x); o[1] = f2bf(v.y); o[2] = f2bf(v.z); o[3] = f2bf(v.w);
        *(us4*)(xb + (size_t)row * FEAT + (size_t)(lane + i * 64) * 4) = o;
    }
#pragma unroll
    for (int off = 32; off; off >>= 1) s += __shfl_xor(s, off);
    if (lane == 0) xsq[row] = s;
}

// K2a: protos (1000x1024 f32) -> bf16 padded to 1024 rows (pad = 0)
__global__ __launch_bounds__(256) void k_prep_protos(const float* __restrict__ p,
                                                     unsigned short* __restrict__ pb) {
    int row = blockIdx.x;
    int t = threadIdx.x;
    us4 o;
    if (row < NALL) {
        float4 v = ((const float4*)(p + (size_t)row * FEAT))[t];
        o[0] = f2bf(v.x); o[1] = f2bf(v.y); o[2] = f2bf(v.z); o[3] = f2bf(v.w);
    } else {
        o[0] = 0; o[1] = 0; o[2] = 0; o[3] = 0;
    }
    *(us4*)(pb + (size_t)row * FEAT + (size_t)t * 4) = o;
}

// K2b: enc_w (1024x1024 f32) -> transposed bf16 (wt[n][k] = enc_w[k][n])
__global__ __launch_bounds__(256) void k_transpose_w(const float* __restrict__ w,
                                                     unsigned short* __restrict__ wt) {
    __shared__ float tile[32][33];
    int bx = blockIdx.x, by = blockIdx.y;
    int tx = threadIdx.x & 31, ty = threadIdx.x >> 5;
#pragma unroll
    for (int i = 0; i < 4; ++i) {
        int r = by * 32 + ty + i * 8;
        tile[ty + i * 8][tx] = w[(size_t)r * FEAT + bx * 32 + tx];
    }
    __syncthreads();
#pragma unroll
    for (int i = 0; i < 4; ++i) {
        int r = bx * 32 + ty + i * 8;
        wt[(size_t)r * FEAT + by * 32 + tx] = f2bf(tile[tx][ty + i * 8]);
    }
}

// K2c: encoder GEMM: ep = protos @ enc_w + b. Writes epb rows in class-major
// permuted order: n' = (n%100)*10 + n/100.
__global__ __launch_bounds__(256) void k_enc_gemm(const unsigned short* __restrict__ A,
                                                  const unsigned short* __restrict__ B,
                                                  const float* __restrict__ bias,
                                                  unsigned short* __restrict__ epb) {
    __shared__ __align__(16) char smem[32768];
    int bm0 = (blockIdx.x >> 3) * 128;
    int bn0 = (blockIdx.x & 7) * 128;
    int tid = threadIdx.x, lane = tid & 63, wid = tid >> 6;
    int wm = wid >> 1, wn = wid & 1;
    int ls = lane >> 4, lf = lane & 15;
    f32x4 acc[4][4] = {};
    for (int k0 = 0; k0 < FEAT; k0 += 64) {
        __syncthreads();
#pragma unroll
        for (int i = 0; i < 4; ++i) {
            int ci = wid + i * 4;
            int r = ci * 8 + (lane >> 3), c = (lane & 7) * 8;
            gload16(A + (size_t)(bm0 + r) * FEAT + k0 + c, smem + ci * 1024);
            gload16(B + (size_t)(bn0 + r) * FEAT + k0 + c, smem + 16384 + ci * 1024);
        }
        __syncthreads();
#pragma unroll
        for (int kk = 0; kk < 64; kk += 32) {
            short8 a[4], b[4];
#pragma unroll
            for (int f = 0; f < 4; ++f) {
                a[f] = *(const short8*)(smem + (wm * 64 + f * 16 + lf) * 128 + (kk + ls * 8) * 2);
                b[f] = *(const short8*)(smem + 16384 + (wn * 64 + f * 16 + lf) * 128 + (kk + ls * 8) * 2);
            }
#pragma unroll
            for (int fm = 0; fm < 4; ++fm)
#pragma unroll
                for (int fn = 0; fn < 4; ++fn)
                    acc[fm][fn] = __builtin_amdgcn_mfma_f32_16x16x32_bf16(a[fm], b[fn], acc[fm][fn], 0, 0, 0);
        }
    }
    int tr = ls * 4, tc = lf;
#pragma unroll
    for (int fn = 0; fn < 4; ++fn) {
        int col = bn0 + wn * 64 + fn * 16 + tc;
        float bb = bias[col];
#pragma unroll
        for (int fm = 0; fm < 4; ++fm) {
#pragma unroll
            for (int r = 0; r < 4; ++r) {
                int row = bm0 + wm * 64 + fm * 16 + tr + r;
                if (row < NALL) {
                    int pr = (row % 100) * 10 + row / 100;
                    epb[(size_t)pr * FEAT + col] = f2bf(acc[fm][fn][r] + bb);
                }
            }
        }
    }
}

// K2d: p_sq per (permuted) ep row; pad rows get 1e30
__global__ __launch_bounds__(256) void k_psq(const unsigned short* __restrict__ epb,
                                             float* __restrict__ psq) {
    int row = blockIdx.x * 4 + (threadIdx.x >> 6);
    int lane = threadIdx.x & 63;
    if (row >= NPAD) return;
    float s = 0.f;
    const short8* r8 = (const short8*)(epb + (size_t)row * FEAT);
#pragma unroll
    for (int i = 0; i < 2; ++i) {
        short8 v = r8[lane + i * 64];
#pragma unroll
        for (int j = 0; j < 8; ++j) {
            union { uint32_t u; float f; } c;
            c.u = ((uint32_t)(unsigned short)v[j]) << 16;
            s += c.f * c.f;
        }
    }
#pragma unroll
    for (int off = 32; off; off >>= 1) s += __shfl_xor(s, off);
    if (lane == 0) psq[row] = (row < NALL) ? s : 1e30f;
}

// K3: main GEMM (16384 x 1120 x 1024) + fused sqrt + min-over-10-protos epilogue.
// BM=256, BN=160, BK=32 subtiles, 4-deep LDS ring, 512 threads (8 waves, 4Mx2N),
// counted-vmcnt pipeline (T3+T4) + setprio (T5) + swizzled LDS (T2, rule 21).
__global__ __launch_bounds__(512) void k_main(const unsigned short* __restrict__ xb,
                                              const unsigned short* __restrict__ epb,
                                              const float* __restrict__ xsq,
                                              const float* __restrict__ psq,
                                              float* __restrict__ out) {
    __shared__ __align__(16) char smem[116352];
    const int bid = blockIdx.x;                     // 448 blocks
    const int swz = (bid & 7) * 56 + (bid >> 3);    // XCD-chunk swizzle (448 % 8 == 0)
    const int bm0 = (swz / 7) * 256;
    const int bn0 = (swz % 7) * 160;
    const int tid = threadIdx.x, lane = tid & 63, wid = tid >> 6;
    const int wm = wid >> 1, wn = wid & 1;          // 4M x 2N wave grid
    const int ls = lane >> 4, lf = lane & 15;
    float* xsq_s = (float*)(smem + 114688);         // 256 f32
    float* psq_s = (float*)(smem + 115712);         // 160 f32
    if (tid < 256) xsq_s[tid] = xsq[bm0 + tid];
    if (tid < 160) psq_s[tid] = psq[bn0 + tid];

    // ---- staging setup (rule 21: linear LDS dest, inverse-swizzled global src) ----
    // chunk = 1 KB = 16 rows x 64 B. lane l: dest row_in_chunk = l>>2, slot = l&3.
    // LDS[row][slot] holds logical k-block c = slot ^ ((row>>1)&3).
    const int sr  = lane >> 2;                          // row within chunk
    const int scb = (lane & 3) ^ ((lane >> 3) & 3);     // source k-block (8 bf16)
    const unsigned short* sp[4];
    int ldo[4];
    if (wid < 4) {           // A-stagers: 16 chunks over 4 waves, 4 each
#pragma unroll
        for (int i = 0; i < 4; ++i) {
            int ci = wid + i * 4;
            sp[i]  = xb + (size_t)(bm0 + ci * 16 + sr) * FEAT + scb * 8;
            ldo[i] = ci * 1024;
        }
    } else {                 // B-stagers: 12 chunks (192 rows) over 4 waves, 3 each
#pragma unroll
        for (int i = 0; i < 3; ++i) {
            int ci = (wid - 4) + i * 4;
            sp[i]  = epb + (size_t)(bn0 + ci * 16 + sr) * FEAT + scb * 8;
            ldo[i] = 16384 + ci * 1024;
        }
        sp[3] = nullptr; ldo[3] = 0;
    }

#define STAGE(S) do {                                                          \
    char* bb_ = smem + ((S) & 3) * LDSBUF;                                     \
    if (wid < 4) {                                                             \
        _Pragma("unroll")                                                      \
        for (int i_ = 0; i_ < 4; ++i_)                                         \
            gload16(sp[i_] + (S) * 32, bb_ + ldo[i_]);                         \
    } else {                                                                   \
        _Pragma("unroll")                                                      \
        for (int i_ = 0; i_ < 3; ++i_)                                         \
            gload16(sp[i_] + (S) * 32, bb_ + ldo[i_]);                         \
    }                                                                          \
} while (0)

    // ---- read-side addresses (swizzled) ----
    const int sw2 = (lf >> 1) & 3;
    const int off = ((ls ^ sw2) << 4);     // step-independent slot offset
    int raA[4], raB[5];
#pragma unroll
    for (int f = 0; f < 4; ++f) raA[f] = (wm * 64 + f * 16 + lf) * 64 + off;
#pragma unroll
    for (int f = 0; f < 5; ++f) raB[f] = 16384 + (wn * 80 + f * 16 + lf) * 64 + off;

    f32x4 acc[4][5] = {};

    STAGE(0); STAGE(1); STAGE(2);
    if (wid < 4) asm volatile("s_waitcnt vmcnt(8)" ::: "memory");
    else         asm volatile("s_waitcnt vmcnt(6)" ::: "memory");
    __builtin_amdgcn_s_barrier();

#pragma unroll
    for (int s = 0; s < 32; ++s) {
        const char* base = (const char*)smem + (s & 3) * LDSBUF;
        short8 a[4], b[5];
#pragma unroll
        for (int f = 0; f < 4; ++f) a[f] = *(const short8*)(base + raA[f]);
#pragma unroll
        for (int f = 0; f < 5; ++f) b[f] = *(const short8*)(base + raB[f]);
        if (s + 3 < 32) STAGE(s + 3);
        // counted vmcnt: ensure subtile s+1's loads landed; allow later batches in flight
        if (s <= 28) {
            if (wid < 4) asm volatile("s_waitcnt vmcnt(8)" ::: "memory");
            else         asm volatile("s_waitcnt vmcnt(6)" ::: "memory");
        } else if (s == 29) {
            if (wid < 4) asm volatile("s_waitcnt vmcnt(4)" ::: "memory");
            else         asm volatile("s_waitcnt vmcnt(3)" ::: "memory");
        } else if (s == 30) {
            asm volatile("s_waitcnt vmcnt(0)" ::: "memory");
        }
        __builtin_amdgcn_s_setprio(1);
#pragma unroll
        for (int fm = 0; fm < 4; ++fm)
#pragma unroll
            for (int fn = 0; fn < 5; ++fn)
                acc[fm][fn] = __builtin_amdgcn_mfma_f32_16x16x32_bf16(a[fm], b[fn], acc[fm][fn], 0, 0, 0);
        __builtin_amdgcn_s_setprio(0);
        __builtin_amdgcn_s_barrier();
    }
#undef STAGE

    // ---- epilogue: d = sqrt(max(xsq - 2*dot + psq, 0)); min over 10 protos ----
    float* dls = (float*)smem;             // [64][161] f32 per pass (41216 B)
    const int tr = ls * 4;
    const int cls0 = bn0 / 10;
#pragma unroll
    for (int p = 0; p < 4; ++p) {          // p == fm
#pragma unroll
        for (int fn = 0; fn < 5; ++fn) {
            int col = wn * 80 + fn * 16 + lf;
            float pq = psq_s[col];
#pragma unroll
            for (int r = 0; r < 4; ++r) {
                float d2 = xsq_s[wm * 64 + p * 16 + tr + r] - 2.f * acc[p][fn][r] + pq;
                dls[(wm * 16 + tr + r) * 161 + col] = sqrtf(fmaxf(d2, 0.f));
            }
        }
        __syncthreads();
#pragma unroll
        for (int i = 0; i < 2; ++i) {
            int task = tid + i * 512;      // 1024 tasks: 64 rows x 16 classes
            int rr = task >> 4, cl = task & 15;
            float m = 1e30f;
#pragma unroll
            for (int j = 0; j < 10; ++j) m = fminf(m, dls[rr * 161 + cl * 10 + j]);
            int grow = bm0 + (rr >> 4) * 64 + p * 16 + (rr & 15);
            int gcls = cls0 + cl;
            if (gcls < NCLS) out[(size_t)grow * NCLS + gcls] = m;
        }
        if (p < 3) __syncthreads();
    }
}

extern "C" void kernel_launch(void* const* d_in, const int* in_sizes, int n_in,
                              void* d_out, int out_size, void* d_ws, size_t ws_size,
                              hipStream_t stream) {
    const float* x      = (const float*)d_in[0];
    const float* protos = (const float*)d_in[1];
    const float* enc_w  = (const float*)d_in[2];
    const float* enc_b  = (const float*)d_in[3];
    float* out = (float*)d_out;
    char* ws = (char*)d_ws;

    unsigned short* xb  = (unsigned short*)ws;                   // 16384*1024*2 = 33554432
    unsigned short* epb = (unsigned short*)(ws + 33554432);      // 1152*1024*2  = 2359296
    unsigned short* prb = (unsigned short*)(ws + 35913728);      // 1024*1024*2  = 2097152
    unsigned short* wtb = (unsigned short*)(ws + 38010880);      // 1024*1024*2  = 2097152
    float* xsq = (float*)(ws + 40108032);                        // 16384*4
    float* psq = (float*)(ws + 40173568);                        // 1120*4

    // zero padded ep rows (1000..1151) so staging reads defined data
    hipMemsetAsync(epb + (size_t)1000 * FEAT, 0, (size_t)152 * FEAT * 2, stream);

    k_prep_x<<<4096, 256, 0, stream>>>(x, xb, xsq);
    k_prep_protos<<<1024, 256, 0, stream>>>(protos, prb);
    k_transpose_w<<<dim3(32, 32), 256, 0, stream>>>(enc_w, wtb);
    k_enc_gemm<<<64, 256, 0, stream>>>(prb, wtb, enc_b, epb);
    k_psq<<<280, 256, 0, stream>>>(epb, psq);
    k_main<<<448, 512, 0, stream>>>(xb, epb, xsq, psq, out);
}